// Round 15
// baseline (1957.186 us; speedup 1.0000x reference)
//
#include <hip/hip_runtime.h>
#include <hip/hip_bf16.h>
#include <cmath>

// Problem constants
constexpr int   BB  = 128;    // batch (GEMM M)
constexpr int   LL  = 128;    // timesteps
constexpr int   NH  = 2048;   // hidden (GEMM N)
constexpr int   KD  = 2048;   // reduction dim
constexpr float DTc   = 0.042f;
constexpr float THETAc= 0.1f;
constexpr float ALPHAc= 0.3f;
constexpr float BETAc = 0.4f;
constexpr size_t S = (size_t)BB * NH;   // 262144

typedef float f32x4 __attribute__((ext_vector_type(4)));
typedef short s16x8 __attribute__((ext_vector_type(8)));

__device__ inline ushort f2bf(float f) {
    union { __hip_bfloat16 h; ushort u; } v; v.h = __float2bfloat16(f); return v.u;
}
__device__ inline float bf2f(ushort u) {
    union { ushort u; __hip_bfloat16 h; } v; v.u = u; return __bfloat162float(v.h);
}
// Exact 3-way bf16 split: f == b1 + b2 + b3
__device__ inline void split3(float f, ushort& b1, ushort& b2, ushort& b3) {
    b1 = f2bf(f);  float r  = f - bf2f(b1);
    b2 = f2bf(r);  float r2 = r - bf2f(b2);
    b3 = f2bf(r2);
}

// Fragment layouts (16x16x32 bf16 MFMA), pre-swizzled global storage
// (SEPARATE split arrays: lane-stride 16B -> fully coalesced):
//   Af: idx = ((kt*4+g)*128 + m)*8 + e          (S shorts per split)
//   Bf: idx = ((kt*128 + nb)*64 + lane)*8 + e   (16S shorts per split)
__global__ __launch_bounds__(256) void packB_kernel(
    const float* __restrict__ W, ushort* __restrict__ B1,
    ushort* __restrict__ B2, ushort* __restrict__ B3)
{
    const int gw   = blockIdx.x * 4 + (threadIdx.x >> 6);
    const int lane = threadIdx.x & 63;
    const int kt = gw >> 7;
    const int nb = gw & 127;
    const size_t ob = ((size_t)(kt * 128 + nb) * 64 + lane) * 8;
    const int k0 = kt * 32 + (lane >> 4) * 8;
    const int n  = nb * 16 + (lane & 15);
    #pragma unroll
    for (int e = 0; e < 8; ++e) {
        float w = W[(size_t)(k0 + e) * NH + n];
        ushort x1, x2, x3; split3(w, x1, x2, x3);
        B1[ob + e] = x1; B2[ob + e] = x2; B3[ob + e] = x3;
    }
}

// ONE dispatch per timestep; 64x32 output tiles (traffic 147 MB/step vs 196
// at 32x32). Grid 128 blocks x 512 thr; wave w reduces K-chunk [w*256,
// (w+1)*256) over a 64x32 wave-tile (mf=4, nf=2). K-split, kt order, 6-MFMA
// order and the q-sum order are UNCHANGED from the 32x32 version -> every
// output element's fp32 chain is bitwise identical. XCD swizzle: XCD=bid%8
// gets c-tiles [8x, 8x+8) -> read-only 3MB B slice persists in its L2.
__global__ __launch_bounds__(512) void step_fused(
    const ushort* __restrict__ Ai1, const ushort* __restrict__ Ai2,
    const ushort* __restrict__ Ai3, ushort* __restrict__ Ao1,
    ushort* __restrict__ Ao2, ushort* __restrict__ Ao3,
    const ushort* __restrict__ B1, const ushort* __restrict__ B2,
    const ushort* __restrict__ B3,
    float* __restrict__ hy, float* __restrict__ hz,
    float* __restrict__ refb, float* __restrict__ ssum,
    const float* __restrict__ x, const float* __restrict__ x2h,
    const float* __restrict__ bias, const float* __restrict__ gamma,
    const float* __restrict__ eps, int t)
{
    __shared__ float Pred[8][64 * 34];   // 69.6 KB; 34-pad keeps float2 8B-aligned
    const int tid  = threadIdx.x;
    const int lane = tid & 63;
    const int w    = tid >> 6;      // wave = K-chunk q (0..7)
    const int g    = lane >> 4;
    const int r16  = lane & 15;
    const int bid  = blockIdx.x;    // 0..127
    const int mb   = bid >> 6;                         // 0..1  (64-row tile)
    const int c    = (bid & 7) * 8 + ((bid >> 3) & 7); // 0..63 (32-col tile), XCD-pinned
    const int ktb  = w * 8;

    // ---------------- G-phase: per-wave K-chunk gemm ----------------
    f32x4 acc[4][2] = {};
    const size_t aoff = (size_t)(g * 128 + mb * 64 + r16) * 8;   // + mf*128 + kt*4096
    const size_t boff = (size_t)(c * 128 + lane) * 8;            // + nf*512 + kt*65536

    #pragma unroll
    for (int j = 0; j < 8; ++j) {
        const int kt = ktb + j;
        const size_t ab = aoff + (size_t)kt * 4096;
        const size_t bb = boff + (size_t)kt * 65536;
        s16x8 a1[4], a2[4], a3[4], b1[2], b2[2], b3[2];
        #pragma unroll
        for (int mf = 0; mf < 4; ++mf) {
            a1[mf] = *(const s16x8*)(Ai1 + ab + mf * 128);
            a2[mf] = *(const s16x8*)(Ai2 + ab + mf * 128);
            a3[mf] = *(const s16x8*)(Ai3 + ab + mf * 128);
        }
        #pragma unroll
        for (int nf = 0; nf < 2; ++nf) {
            b1[nf] = *(const s16x8*)(B1 + bb + nf * 512);
            b2[nf] = *(const s16x8*)(B2 + bb + nf * 512);
            b3[nf] = *(const s16x8*)(B3 + bb + nf * 512);
        }
        #pragma unroll
        for (int mf = 0; mf < 4; ++mf)
        #pragma unroll
        for (int nf = 0; nf < 2; ++nf) {
            f32x4 cc = acc[mf][nf];
            cc = __builtin_amdgcn_mfma_f32_16x16x32_bf16(a1[mf], b1[nf], cc, 0, 0, 0);
            cc = __builtin_amdgcn_mfma_f32_16x16x32_bf16(a1[mf], b2[nf], cc, 0, 0, 0);
            cc = __builtin_amdgcn_mfma_f32_16x16x32_bf16(a2[mf], b1[nf], cc, 0, 0, 0);
            cc = __builtin_amdgcn_mfma_f32_16x16x32_bf16(a1[mf], b3[nf], cc, 0, 0, 0);
            cc = __builtin_amdgcn_mfma_f32_16x16x32_bf16(a2[mf], b2[nf], cc, 0, 0, 0);
            cc = __builtin_amdgcn_mfma_f32_16x16x32_bf16(a3[mf], b1[nf], cc, 0, 0, 0);
            acc[mf][nf] = cc;
        }
    }

    // partials -> LDS (C-frag: row = mf*16 + g*4 + r, col = nf*16 + r16)
    #pragma unroll
    for (int mf = 0; mf < 4; ++mf)
    #pragma unroll
    for (int nf = 0; nf < 2; ++nf)
    #pragma unroll
    for (int r = 0; r < 4; ++r)
        Pred[w][(mf * 16 + g * 4 + r) * 34 + nf * 16 + r16] = acc[mf][nf][r];

    __syncthreads();

    // ---------------- U-phase: reduce + cell update (4 elems/thread) ----------------
    const int e0  = tid * 4;
    const int row = e0 >> 5;            // 0..63
    const int col = e0 & 31;            // 0,4,...,28
    const int b   = mb * 64 + row;
    const int n0  = c * 32 + col;

    float pa[4] = {0.f, 0.f, 0.f, 0.f};
    #pragma unroll
    for (int q = 0; q < 8; ++q) {       // fixed order == round-14 sum
        const float2 pv0 = *(const float2*)&Pred[q][row * 34 + col];
        const float2 pv1 = *(const float2*)&Pred[q][row * 34 + col + 2];
        pa[0] += pv0.x; pa[1] += pv0.y; pa[2] += pv1.x; pa[3] += pv1.y;
    }

    const size_t ig = (size_t)b * NH + n0;
    const float xt = x[(size_t)b * LL + t];
    const float rd = expf(-DTc / 0.25f);
    const float4 x2hv = *(const float4*)(x2h + n0);
    const float4 biv  = *(const float4*)(bias + n0);
    const float4 gav  = *(const float4*)(gamma + n0);
    const float4 epv  = *(const float4*)(eps + n0);
    float4 hyv = *(float4*)(hy + ig);
    float4 hzv = *(float4*)(hz + ig);
    float4 rfv = *(float4*)(refb + ig);
    float4 ssv = *(float4*)(ssum + ig);

    float hya[4] = {hyv.x, hyv.y, hyv.z, hyv.w};
    float hza[4] = {hzv.x, hzv.y, hzv.z, hzv.w};
    float rfa[4] = {rfv.x, rfv.y, rfv.z, rfv.w};
    float ssa[4] = {ssv.x, ssv.y, ssv.z, ssv.w};
    const float x2a[4] = {x2hv.x, x2hv.y, x2hv.z, x2hv.w};
    const float bia[4] = {biv.x, biv.y, biv.z, biv.w};
    const float gaa[4] = {gav.x, gav.y, gav.z, gav.w};
    const float epa[4] = {epv.x, epv.y, epv.z, epv.w};
    ushort u1a[4], u2a[4], u3a[4];

    #pragma unroll
    for (int i = 0; i < 4; ++i) {
        float pre = tanhf(pa[i] + xt * x2a[i] + bia[i]);
        hza[i] += DTc * (pre - gaa[i] * hya[i] - epa[i] * hza[i]);
        hya[i] += DTc * hza[i];
        float s = (hya[i] - THETAc - rfa[i] > 0.f) ? 1.f : 0.f;
        hya[i] *= 1.f - s * ALPHAc;
        hza[i] *= 1.f - s * BETAc;
        rfa[i] = rfa[i] * rd + s;
        ssa[i] += s;
        split3(hya[i], u1a[i], u2a[i], u3a[i]);
    }

    // A-split writes: 4 consecutive n share (kt,g) and have consecutive e -> ushort4
    {
        const int kt0 = n0 >> 5, gg = (n0 >> 3) & 3, ee = n0 & 7;  // ee in {0,4}
        const size_t o = ((size_t)(kt0 * 4 + gg) * 128 + b) * 8 + ee;
        *(ushort4*)(Ao1 + o) = make_ushort4(u1a[0], u1a[1], u1a[2], u1a[3]);
        *(ushort4*)(Ao2 + o) = make_ushort4(u2a[0], u2a[1], u2a[2], u2a[3]);
        *(ushort4*)(Ao3 + o) = make_ushort4(u3a[0], u3a[1], u3a[2], u3a[3]);
    }

    *(float4*)(hy + ig)   = make_float4(hya[0], hya[1], hya[2], hya[3]);
    *(float4*)(hz + ig)   = make_float4(hza[0], hza[1], hza[2], hza[3]);
    *(float4*)(refb + ig) = make_float4(rfa[0], rfa[1], rfa[2], rfa[3]);
    *(float4*)(ssum + ig) = make_float4(ssa[0], ssa[1], ssa[2], ssa[3]);
}

__global__ __launch_bounds__(512) void finish_kernel(const float* __restrict__ ssum,
                                                     float* __restrict__ out)
{
    const int i = blockIdx.x * 512 + threadIdx.x;
    out[i] = ssum[i] * (1.0f / (float)LL);
}

// ---------------- fallback vector path (small workspace) ----------------
template<int KCH>
__global__ __launch_bounds__(512) void gemm_vec(
    const float* __restrict__ hy_in, float* __restrict__ P,
    const float* __restrict__ W)
{
    const int lane = threadIdx.x & 63;
    const int w    = __builtin_amdgcn_readfirstlane((int)(threadIdx.x >> 6));
    const int n        = blockIdx.x * 64 + lane;
    const int rowbase  = blockIdx.y * 64 + w * 8;
    const int kq       = blockIdx.z;
    const int k0       = kq * KCH;
    const float* __restrict__ hp = hy_in + (size_t)rowbase * KD + k0;
    const float* __restrict__ Wp = W + (size_t)k0 * NH + n;
    float acc[8] = {0.f,0.f,0.f,0.f,0.f,0.f,0.f,0.f};
    float wc[8], w1[8], w2[8];
    #pragma unroll
    for (int i = 0; i < 8; ++i) w1[i] = Wp[(size_t)i * NH];
    {
        const float* Wq = Wp + (size_t)8 * NH;
        #pragma unroll
        for (int i = 0; i < 8; ++i) w2[i] = Wq[(size_t)i * NH];
    }
    for (int k = 0; k < KCH; k += 8) {
        #pragma unroll
        for (int i = 0; i < 8; ++i) wc[i] = w1[i];
        #pragma unroll
        for (int i = 0; i < 8; ++i) w1[i] = w2[i];
        if (k + 16 < KCH) {
            const float* Wq = Wp + (size_t)(k + 16) * NH;
            #pragma unroll
            for (int i = 0; i < 8; ++i) w2[i] = Wq[(size_t)i * NH];
        }
        #pragma unroll
        for (int j = 0; j < 8; ++j) {
            const float* hr = hp + (size_t)j * KD + k;
            float4 a = *(const float4*)(hr);
            float4 bq = *(const float4*)(hr + 4);
            acc[j] = fmaf(a.x, wc[0], acc[j]);  acc[j] = fmaf(a.y, wc[1], acc[j]);
            acc[j] = fmaf(a.z, wc[2], acc[j]);  acc[j] = fmaf(a.w, wc[3], acc[j]);
            acc[j] = fmaf(bq.x, wc[4], acc[j]); acc[j] = fmaf(bq.y, wc[5], acc[j]);
            acc[j] = fmaf(bq.z, wc[6], acc[j]); acc[j] = fmaf(bq.w, wc[7], acc[j]);
        }
    }
    float* Pp = P + ((size_t)kq * BB + rowbase) * NH + n;
    #pragma unroll
    for (int j = 0; j < 8; ++j) Pp[(size_t)j * NH] = acc[j];
}

__global__ __launch_bounds__(256) void update_vec(
    const float* __restrict__ P, int kqn, const float* __restrict__ hy_in,
    float* __restrict__ hy_out, float* __restrict__ hz,
    float* __restrict__ refb, float* __restrict__ ssum,
    const float* __restrict__ x2h, const float* __restrict__ bias,
    const float* __restrict__ gamma, const float* __restrict__ eps,
    const float* __restrict__ x, int t)
{
    const int i = blockIdx.x * 256 + threadIdx.x;
    const int b = i >> 11;
    const int n = i & (NH - 1);
    float acc = 0.f;
    for (int q = 0; q < kqn; ++q) acc += P[(size_t)q * S + i];
    const float xt = x[(size_t)b * LL + t];
    float pre = tanhf(acc + xt * x2h[n] + bias[n]);
    float hyv = hy_in[i];
    float hzv = hz[i];
    float rf  = refb[i];
    const float rd = expf(-DTc / 0.25f);
    hzv += DTc * (pre - gamma[n] * hyv - eps[n] * hzv);
    hyv += DTc * hzv;
    float s = (hyv - THETAc - rf > 0.f) ? 1.f : 0.f;
    hyv *= 1.f - s * ALPHAc;
    hzv *= 1.f - s * BETAc;
    rf = rf * rd + s;
    hy_out[i] = hyv; hz[i] = hzv; refb[i] = rf; ssum[i] += s;
}

extern "C" void kernel_launch(void* const* d_in, const int* in_sizes, int n_in,
                              void* d_out, int out_size, void* d_ws, size_t ws_size,
                              hipStream_t stream) {
    const float* x     = (const float*)d_in[0];
    const float* W     = (const float*)d_in[1];
    const float* x2h   = (const float*)d_in[2];
    const float* bias  = (const float*)d_in[3];
    const float* gamma = (const float*)d_in[4];
    const float* eps   = (const float*)d_in[5];
    float* out = (float*)d_out;

    const size_t SB = S * sizeof(float);   // 1 MB

    // layout: [Aa(3S u16)=1.5MB][hy][hz][rf][ss]=4MB | [Ab(3S u16)=1.5MB] | B(24MB)
    const size_t offSt  = 3 * S * 2;
    const size_t offAb  = offSt + 4 * SB;
    const size_t offB   = offAb + 3 * S * 2;
    const size_t need   = offB + 3 * (16 * S) * 2;

    if (ws_size >= need) {
        char* base = (char*)d_ws;
        ushort* Aa1 = (ushort*)base;
        ushort* Aa2 = Aa1 + S;
        ushort* Aa3 = Aa2 + S;
        float*  hy = (float*)(base + offSt);
        float*  hz = hy + S;
        float*  rf = hz + S;
        float*  ss = rf + S;
        ushort* Ab1 = (ushort*)(base + offAb);
        ushort* Ab2 = Ab1 + S;
        ushort* Ab3 = Ab2 + S;
        ushort* B1 = (ushort*)(base + offB);
        ushort* B2 = B1 + 16 * S;
        ushort* B3 = B2 + 16 * S;

        // zero Aa (hy(0)=0 -> zero frags) + states (5.5MB); Ab fully written at t=0
        hipMemsetAsync(d_ws, 0, offAb, stream);

        packB_kernel<<<2048, 256, 0, stream>>>(W, B1, B2, B3);

        ushort *i1 = Aa1, *i2 = Aa2, *i3 = Aa3, *o1 = Ab1, *o2 = Ab2, *o3 = Ab3;
        for (int t = 0; t < LL; ++t) {
            step_fused<<<128, 512, 0, stream>>>(i1, i2, i3, o1, o2, o3,
                                                B1, B2, B3, hy, hz, rf, ss,
                                                x, x2h, bias, gamma, eps, t);
            ushort* tp;
            tp = i1; i1 = o1; o1 = tp;
            tp = i2; i2 = o2; o2 = tp;
            tp = i3; i3 = o3; o3 = tp;
        }
        finish_kernel<<<(unsigned)(S / 512), 512, 0, stream>>>(ss, out);
    } else {
        // vector fallback
        float* ws = (float*)d_ws;
        float* hyA = ws;
        float* hz  = ws + S;
        float* rf  = ws + 2 * S;
        float* ss  = ws + 3 * S;
        float* hyB = ws + 4 * S;
        float* P   = ws + 5 * S;
        const int kq = (ws_size >= 13 * SB) ? 8 : 4;
        hipMemsetAsync(d_ws, 0, 4 * SB, stream);
        dim3 ggrid(NH / 64, BB / 64, kq);
        const float* hin = hyA;
        float* hout = hyB;
        for (int t = 0; t < LL; ++t) {
            if (kq == 8)
                gemm_vec<KD / 8><<<ggrid, 512, 0, stream>>>(hin, P, W);
            else
                gemm_vec<KD / 4><<<ggrid, 512, 0, stream>>>(hin, P, W);
            update_vec<<<(unsigned)(S / 256), 256, 0, stream>>>(
                P, kq, hin, hout, hz, rf, ss, x2h, bias, gamma, eps, x, t);
            const float* tmp = hout; hout = (float*)hin; hin = tmp;
        }
        finish_kernel<<<(unsigned)(S / 512), 512, 0, stream>>>(ss, out);
    }
}

// Round 16
// 1707.898 us; speedup vs baseline: 1.1460x; 1.1460x over previous
//
#include <hip/hip_runtime.h>
#include <hip/hip_bf16.h>
#include <cmath>

// Problem constants
constexpr int   BB  = 128;    // batch (GEMM M)
constexpr int   LL  = 128;    // timesteps
constexpr int   NH  = 2048;   // hidden (GEMM N)
constexpr int   KD  = 2048;   // reduction dim
constexpr float DTc   = 0.042f;
constexpr float THETAc= 0.1f;
constexpr float ALPHAc= 0.3f;
constexpr float BETAc = 0.4f;
constexpr size_t S = (size_t)BB * NH;   // 262144

typedef float f32x4 __attribute__((ext_vector_type(4)));
typedef short s16x8 __attribute__((ext_vector_type(8)));

__device__ inline ushort f2bf(float f) {
    union { __hip_bfloat16 h; ushort u; } v; v.h = __float2bfloat16(f); return v.u;
}
__device__ inline float bf2f(ushort u) {
    union { ushort u; __hip_bfloat16 h; } v; v.u = u; return __bfloat162float(v.h);
}
// Exact 3-way bf16 split: f == b1 + b2 + b3 (residual ~2^-24|f| dropped)
__device__ inline void split3(float f, ushort& b1, ushort& b2, ushort& b3) {
    b1 = f2bf(f);  float r  = f - bf2f(b1);
    b2 = f2bf(r);  float r2 = r - bf2f(b2);
    b3 = f2bf(r2);
}

// Fragment layouts (16x16x32 bf16 MFMA), pre-swizzled global storage
// (SEPARATE split arrays: lane-stride 16B -> fully coalesced; interleaving
// the splits (round 13) tripled VMEM transactions and regressed):
//   Af: idx = ((kt*4+g)*128 + m)*8 + e          (S shorts per split)
//   Bf: idx = ((kt*128 + nb)*64 + lane)*8 + e   (16S shorts per split)
__global__ __launch_bounds__(256) void packB_kernel(
    const float* __restrict__ W, ushort* __restrict__ B1,
    ushort* __restrict__ B2, ushort* __restrict__ B3)
{
    const int gw   = blockIdx.x * 4 + (threadIdx.x >> 6);
    const int lane = threadIdx.x & 63;
    const int kt = gw >> 7;
    const int nb = gw & 127;
    const size_t ob = ((size_t)(kt * 128 + nb) * 64 + lane) * 8;
    const int k0 = kt * 32 + (lane >> 4) * 8;
    const int n  = nb * 16 + (lane & 15);
    #pragma unroll
    for (int e = 0; e < 8; ++e) {
        float w = W[(size_t)(k0 + e) * NH + n];
        ushort x1, x2, x3; split3(w, x1, x2, x3);
        B1[ob + e] = x1; B2[ob + e] = x2; B3[ob + e] = x3;
    }
}

// ONE dispatch per timestep: gemm (K split across the 8 waves, LDS-reduced)
// + cell update fused; the final step also writes `out` (finish fused).
// Grid 256 blocks x 512 thr; block = 32x32 output tile. XCD-aware swizzle:
// default dispatch maps bid -> XCD bid%8; c = (bid&7)*8 + ((bid>>3)&7) pins
// each XCD to 8 c-tiles -> its 3MB read-only B slice persists in its L2
// across all 128 dispatches.
__global__ __launch_bounds__(512) void step_fused(
    const ushort* __restrict__ Ai1, const ushort* __restrict__ Ai2,
    const ushort* __restrict__ Ai3, ushort* __restrict__ Ao1,
    ushort* __restrict__ Ao2, ushort* __restrict__ Ao3,
    const ushort* __restrict__ B1, const ushort* __restrict__ B2,
    const ushort* __restrict__ B3,
    float* __restrict__ hy, float* __restrict__ hz,
    float* __restrict__ refb, float* __restrict__ ssum,
    const float* __restrict__ x, const float* __restrict__ x2h,
    const float* __restrict__ bias, const float* __restrict__ gamma,
    const float* __restrict__ eps, float* __restrict__ out, int t)
{
    __shared__ float Pred[8][32 * 34];   // 34-pad: 8B-aligned float2 rows, low conflict
    const int tid  = threadIdx.x;
    const int lane = tid & 63;
    const int w    = tid >> 6;      // wave = K-chunk q (0..7)
    const int g    = lane >> 4;
    const int r16  = lane & 15;
    const int bid  = blockIdx.x;
    const int mb   = bid >> 6;                         // 0..3  (32-row tile)
    const int c    = (bid & 7) * 8 + ((bid >> 3) & 7); // 0..63 (32-col tile), XCD-pinned
    const int ktb  = w * 8;

    // ---------------- G-phase: per-wave K-chunk gemm ----------------
    f32x4 acc[2][2] = {};
    const size_t aoff = (size_t)(g * 128 + mb * 32 + r16) * 8;   // + mf*128 + kt*4096
    const size_t boff = (size_t)(c * 128 + lane) * 8;            // + nf*512 + kt*65536

    #pragma unroll
    for (int j = 0; j < 8; ++j) {
        const int kt = ktb + j;
        const size_t ab = aoff + (size_t)kt * 4096;
        const size_t bb = boff + (size_t)kt * 65536;
        s16x8 a1[2], a2[2], a3[2], b1[2], b2[2], b3[2];
        #pragma unroll
        for (int mf = 0; mf < 2; ++mf) {
            a1[mf] = *(const s16x8*)(Ai1 + ab + mf * 128);
            a2[mf] = *(const s16x8*)(Ai2 + ab + mf * 128);
            a3[mf] = *(const s16x8*)(Ai3 + ab + mf * 128);
        }
        #pragma unroll
        for (int nf = 0; nf < 2; ++nf) {
            b1[nf] = *(const s16x8*)(B1 + bb + nf * 512);
            b2[nf] = *(const s16x8*)(B2 + bb + nf * 512);
            b3[nf] = *(const s16x8*)(B3 + bb + nf * 512);
        }
        #pragma unroll
        for (int mf = 0; mf < 2; ++mf)
        #pragma unroll
        for (int nf = 0; nf < 2; ++nf) {
            f32x4 cc = acc[mf][nf];
            cc = __builtin_amdgcn_mfma_f32_16x16x32_bf16(a1[mf], b1[nf], cc, 0, 0, 0);
            cc = __builtin_amdgcn_mfma_f32_16x16x32_bf16(a1[mf], b2[nf], cc, 0, 0, 0);
            cc = __builtin_amdgcn_mfma_f32_16x16x32_bf16(a2[mf], b1[nf], cc, 0, 0, 0);
            cc = __builtin_amdgcn_mfma_f32_16x16x32_bf16(a1[mf], b3[nf], cc, 0, 0, 0);
            cc = __builtin_amdgcn_mfma_f32_16x16x32_bf16(a2[mf], b2[nf], cc, 0, 0, 0);
            cc = __builtin_amdgcn_mfma_f32_16x16x32_bf16(a3[mf], b1[nf], cc, 0, 0, 0);
            acc[mf][nf] = cc;
        }
    }

    // partials -> LDS (C-frag: row = mf*16 + g*4 + r, col = nf*16 + r16)
    #pragma unroll
    for (int mf = 0; mf < 2; ++mf)
    #pragma unroll
    for (int nf = 0; nf < 2; ++nf)
    #pragma unroll
    for (int r = 0; r < 4; ++r)
        Pred[w][(mf * 16 + g * 4 + r) * 34 + nf * 16 + r16] = acc[mf][nf][r];

    __syncthreads();

    // ---------------- U-phase: reduce + cell update ----------------
    const int e0  = tid * 2;            // two adjacent cols of one row
    const int row = e0 >> 5;
    const int col = e0 & 31;
    const int b   = mb * 32 + row;
    const int n0  = c * 32 + col, n1 = n0 + 1;

    float pa0 = 0.f, pa1 = 0.f;
    #pragma unroll
    for (int q = 0; q < 8; ++q) {       // fixed order (numerics anchor)
        const float2 pv = *(const float2*)&Pred[q][row * 34 + col];
        pa0 += pv.x; pa1 += pv.y;
    }

    const size_t ig = (size_t)b * NH + n0;
    const float xt = x[(size_t)b * LL + t];
    const float rd = expf(-DTc / 0.25f);
    const float2 x2hv = *(const float2*)(x2h + n0);
    const float2 biv  = *(const float2*)(bias + n0);
    const float2 gav  = *(const float2*)(gamma + n0);
    const float2 epv  = *(const float2*)(eps + n0);
    float2 hyv = *(float2*)(hy + ig);
    float2 hzv = *(float2*)(hz + ig);
    float2 rfv = *(float2*)(refb + ig);
    float2 ssv = *(float2*)(ssum + ig);

    {
        float pre = tanhf(pa0 + xt * x2hv.x + biv.x);
        hzv.x += DTc * (pre - gav.x * hyv.x - epv.x * hzv.x);
        hyv.x += DTc * hzv.x;
        float s = (hyv.x - THETAc - rfv.x > 0.f) ? 1.f : 0.f;
        hyv.x *= 1.f - s * ALPHAc;
        hzv.x *= 1.f - s * BETAc;
        rfv.x = rfv.x * rd + s;
        ssv.x += s;
        ushort u1, u2, u3; split3(hyv.x, u1, u2, u3);
        const int kt0 = n0 >> 5, gg = (n0 >> 3) & 3, ee = n0 & 7;
        const size_t o = ((size_t)(kt0 * 4 + gg) * 128 + b) * 8 + ee;
        Ao1[o] = u1; Ao2[o] = u2; Ao3[o] = u3;
    }
    {
        float pre = tanhf(pa1 + xt * x2hv.y + biv.y);
        hzv.y += DTc * (pre - gav.y * hyv.y - epv.y * hzv.y);
        hyv.y += DTc * hzv.y;
        float s = (hyv.y - THETAc - rfv.y > 0.f) ? 1.f : 0.f;
        hyv.y *= 1.f - s * ALPHAc;
        hzv.y *= 1.f - s * BETAc;
        rfv.y = rfv.y * rd + s;
        ssv.y += s;
        ushort u1, u2, u3; split3(hyv.y, u1, u2, u3);
        const int kt1 = n1 >> 5, gg = (n1 >> 3) & 3, ee = n1 & 7;
        const size_t o = ((size_t)(kt1 * 4 + gg) * 128 + b) * 8 + ee;
        Ao1[o] = u1; Ao2[o] = u2; Ao3[o] = u3;
    }

    *(float2*)(hy + ig)   = hyv;
    *(float2*)(hz + ig)   = hzv;
    *(float2*)(refb + ig) = rfv;
    *(float2*)(ssum + ig) = ssv;

    if (t == LL - 1) {   // fused finish: mean spike rate
        out[ig]     = ssv.x * (1.0f / (float)LL);
        out[ig + 1] = ssv.y * (1.0f / (float)LL);
    }
}

// ---------------- fallback vector path (small workspace) ----------------
template<int KCH>
__global__ __launch_bounds__(512) void gemm_vec(
    const float* __restrict__ hy_in, float* __restrict__ P,
    const float* __restrict__ W)
{
    const int lane = threadIdx.x & 63;
    const int w    = __builtin_amdgcn_readfirstlane((int)(threadIdx.x >> 6));
    const int n        = blockIdx.x * 64 + lane;
    const int rowbase  = blockIdx.y * 64 + w * 8;
    const int kq       = blockIdx.z;
    const int k0       = kq * KCH;
    const float* __restrict__ hp = hy_in + (size_t)rowbase * KD + k0;
    const float* __restrict__ Wp = W + (size_t)k0 * NH + n;
    float acc[8] = {0.f,0.f,0.f,0.f,0.f,0.f,0.f,0.f};
    float wc[8], w1[8], w2[8];
    #pragma unroll
    for (int i = 0; i < 8; ++i) w1[i] = Wp[(size_t)i * NH];
    {
        const float* Wq = Wp + (size_t)8 * NH;
        #pragma unroll
        for (int i = 0; i < 8; ++i) w2[i] = Wq[(size_t)i * NH];
    }
    for (int k = 0; k < KCH; k += 8) {
        #pragma unroll
        for (int i = 0; i < 8; ++i) wc[i] = w1[i];
        #pragma unroll
        for (int i = 0; i < 8; ++i) w1[i] = w2[i];
        if (k + 16 < KCH) {
            const float* Wq = Wp + (size_t)(k + 16) * NH;
            #pragma unroll
            for (int i = 0; i < 8; ++i) w2[i] = Wq[(size_t)i * NH];
        }
        #pragma unroll
        for (int j = 0; j < 8; ++j) {
            const float* hr = hp + (size_t)j * KD + k;
            float4 a = *(const float4*)(hr);
            float4 bq = *(const float4*)(hr + 4);
            acc[j] = fmaf(a.x, wc[0], acc[j]);  acc[j] = fmaf(a.y, wc[1], acc[j]);
            acc[j] = fmaf(a.z, wc[2], acc[j]);  acc[j] = fmaf(a.w, wc[3], acc[j]);
            acc[j] = fmaf(bq.x, wc[4], acc[j]); acc[j] = fmaf(bq.y, wc[5], acc[j]);
            acc[j] = fmaf(bq.z, wc[6], acc[j]); acc[j] = fmaf(bq.w, wc[7], acc[j]);
        }
    }
    float* Pp = P + ((size_t)kq * BB + rowbase) * NH + n;
    #pragma unroll
    for (int j = 0; j < 8; ++j) Pp[(size_t)j * NH] = acc[j];
}

__global__ __launch_bounds__(256) void update_vec(
    const float* __restrict__ P, int kqn, const float* __restrict__ hy_in,
    float* __restrict__ hy_out, float* __restrict__ hz,
    float* __restrict__ refb, float* __restrict__ ssum,
    const float* __restrict__ x2h, const float* __restrict__ bias,
    const float* __restrict__ gamma, const float* __restrict__ eps,
    const float* __restrict__ x, int t)
{
    const int i = blockIdx.x * 256 + threadIdx.x;
    const int b = i >> 11;
    const int n = i & (NH - 1);
    float acc = 0.f;
    for (int q = 0; q < kqn; ++q) acc += P[(size_t)q * S + i];
    const float xt = x[(size_t)b * LL + t];
    float pre = tanhf(acc + xt * x2h[n] + bias[n]);
    float hyv = hy_in[i];
    float hzv = hz[i];
    float rf  = refb[i];
    const float rd = expf(-DTc / 0.25f);
    hzv += DTc * (pre - gamma[n] * hyv - eps[n] * hzv);
    hyv += DTc * hzv;
    float s = (hyv - THETAc - rf > 0.f) ? 1.f : 0.f;
    hyv *= 1.f - s * ALPHAc;
    hzv *= 1.f - s * BETAc;
    rf = rf * rd + s;
    hy_out[i] = hyv; hz[i] = hzv; refb[i] = rf; ssum[i] += s;
}

__global__ __launch_bounds__(512) void finish_kernel(const float* __restrict__ ssum,
                                                     float* __restrict__ out)
{
    const int i = blockIdx.x * 512 + threadIdx.x;
    out[i] = ssum[i] * (1.0f / (float)LL);
}

extern "C" void kernel_launch(void* const* d_in, const int* in_sizes, int n_in,
                              void* d_out, int out_size, void* d_ws, size_t ws_size,
                              hipStream_t stream) {
    const float* x     = (const float*)d_in[0];
    const float* W     = (const float*)d_in[1];
    const float* x2h   = (const float*)d_in[2];
    const float* bias  = (const float*)d_in[3];
    const float* gamma = (const float*)d_in[4];
    const float* eps   = (const float*)d_in[5];
    float* out = (float*)d_out;

    const size_t SB = S * sizeof(float);   // 1 MB

    // layout: [Aa(3S u16)=1.5MB][hy][hz][rf][ss]=4MB | [Ab(3S u16)=1.5MB] | B(24MB)
    const size_t offSt  = 3 * S * 2;
    const size_t offAb  = offSt + 4 * SB;
    const size_t offB   = offAb + 3 * S * 2;
    const size_t need   = offB + 3 * (16 * S) * 2;

    if (ws_size >= need) {
        char* base = (char*)d_ws;
        ushort* Aa1 = (ushort*)base;
        ushort* Aa2 = Aa1 + S;
        ushort* Aa3 = Aa2 + S;
        float*  hy = (float*)(base + offSt);
        float*  hz = hy + S;
        float*  rf = hz + S;
        float*  ss = rf + S;
        ushort* Ab1 = (ushort*)(base + offAb);
        ushort* Ab2 = Ab1 + S;
        ushort* Ab3 = Ab2 + S;
        ushort* B1 = (ushort*)(base + offB);
        ushort* B2 = B1 + 16 * S;
        ushort* B3 = B2 + 16 * S;

        // zero Aa (hy(0)=0 -> zero frags) + states (5.5MB); Ab fully written at t=0
        hipMemsetAsync(d_ws, 0, offAb, stream);

        packB_kernel<<<2048, 256, 0, stream>>>(W, B1, B2, B3);

        ushort *i1 = Aa1, *i2 = Aa2, *i3 = Aa3, *o1 = Ab1, *o2 = Ab2, *o3 = Ab3;
        for (int t = 0; t < LL; ++t) {
            step_fused<<<256, 512, 0, stream>>>(i1, i2, i3, o1, o2, o3,
                                                B1, B2, B3, hy, hz, rf, ss,
                                                x, x2h, bias, gamma, eps, out, t);
            ushort* tp;
            tp = i1; i1 = o1; o1 = tp;
            tp = i2; i2 = o2; o2 = tp;
            tp = i3; i3 = o3; o3 = tp;
        }
    } else {
        // vector fallback
        float* ws = (float*)d_ws;
        float* hyA = ws;
        float* hz  = ws + S;
        float* rf  = ws + 2 * S;
        float* ss  = ws + 3 * S;
        float* hyB = ws + 4 * S;
        float* P   = ws + 5 * S;
        const int kq = (ws_size >= 13 * SB) ? 8 : 4;
        hipMemsetAsync(d_ws, 0, 4 * SB, stream);
        dim3 ggrid(NH / 64, BB / 64, kq);
        const float* hin = hyA;
        float* hout = hyB;
        for (int t = 0; t < LL; ++t) {
            if (kq == 8)
                gemm_vec<KD / 8><<<ggrid, 512, 0, stream>>>(hin, P, W);
            else
                gemm_vec<KD / 4><<<ggrid, 512, 0, stream>>>(hin, P, W);
            update_vec<<<(unsigned)(S / 256), 256, 0, stream>>>(
                P, kq, hin, hout, hz, rf, ss, x2h, bias, gamma, eps, x, t);
            const float* tmp = hout; hout = (float*)hin; hin = tmp;
        }
        finish_kernel<<<(unsigned)(S / 512), 512, 0, stream>>>(ss, out);
    }
}